// Round 1
// baseline (1085.699 us; speedup 1.0000x reference)
//
#include <hip/hip_runtime.h>
#include <math.h>

// Multi-query attention, MI355X gfx950.
// b=8, n=s=1024, d=k=v=256, h=8.
// Split-bf16 (hi/lo) 3-pass MFMA for the pre-softmax chain (fp32-accurate logits);
// plain bf16 MFMA post-softmax.

typedef short bf16x8 __attribute__((ext_vector_type(8)));
typedef float f32x4  __attribute__((ext_vector_type(4)));

#define MFMA(a, b, c) __builtin_amdgcn_mfma_f32_16x16x32_bf16((a), (b), (c), 0, 0, 0)

__device__ __forceinline__ unsigned short f32_bf16(float f) {
  unsigned u = __float_as_uint(f);
  u += 0x7FFFu + ((u >> 16) & 1u);   // RNE
  return (unsigned short)(u >> 16);
}
__device__ __forceinline__ float bf16_f32(unsigned short h) {
  return __uint_as_float(((unsigned)h) << 16);
}

// ---------------------------------------------------------------------------
// Prep: split x,m into bf16 hi/lo; convert output_proj to bf16.
__global__ void k_prep(const float* __restrict__ x, const float* __restrict__ m,
                       const float* __restrict__ op,
                       unsigned short* __restrict__ xh, unsigned short* __restrict__ xl,
                       unsigned short* __restrict__ mh, unsigned short* __restrict__ ml,
                       unsigned short* __restrict__ opb) {
  const int tid = blockIdx.x * blockDim.x + threadIdx.x;
  const int stride = gridDim.x * blockDim.x;
  for (int i = tid; i < 2097152; i += stride) {
    float v = x[i];
    unsigned short h = f32_bf16(v);
    xh[i] = h; xl[i] = f32_bf16(v - bf16_f32(h));
    float w = m[i];
    unsigned short h2 = f32_bf16(w);
    mh[i] = h2; ml[i] = f32_bf16(w - bf16_f32(h2));
  }
  for (int i = tid; i < 524288; i += stride) opb[i] = f32_bf16(op[i]);
}

// ---------------------------------------------------------------------------
// W[h][d'][d] = sum_k Qp[h,d,k]*Kp[d',k]  (fp32, then hi/lo split).
// Stored transposed ([d'][d]) so the t-GEMM B-fragment reads are contiguous.
__global__ void k_w(const float* __restrict__ qp, const float* __restrict__ kp,
                    unsigned short* __restrict__ wh, unsigned short* __restrict__ wl) {
  const int t = blockIdx.x * 256 + threadIdx.x;   // 524288 threads
  const int i = t & 255;          // d   (inner)
  const int j = (t >> 8) & 255;   // d'
  const int h = t >> 16;
  const float* qrow = qp + ((size_t)(h * 256 + i)) * 256;
  const float* krow = kp + (size_t)j * 256;
  float acc = 0.0f;
  for (int k = 0; k < 256; ++k) acc += qrow[k] * krow[k];
  const unsigned short hi = f32_bf16(acc);
  wh[t] = hi;
  wl[t] = f32_bf16(acc - bf16_f32(hi));
}

// ---------------------------------------------------------------------------
// v = m @ value_proj, stored TRANSPOSED: Vt[b][vc][s] (bf16) so PV B-frags are contiguous.
__global__ void k_v(const float* __restrict__ m, const float* __restrict__ vp,
                    unsigned short* __restrict__ vt) {
  const int t = blockIdx.x * 256 + threadIdx.x;   // 2097152 threads
  const int vc = t & 255;
  const int s  = (t >> 8) & 1023;
  const int b  = t >> 18;
  const float* mrow = m + ((size_t)(b * 1024 + s)) * 256;
  float acc = 0.0f;
  for (int d = 0; d < 256; ++d) acc += mrow[d] * vp[d * 256 + vc];
  vt[((size_t)(b * 256 + vc)) * 1024 + s] = f32_bf16(acc);
}

// ---------------------------------------------------------------------------
// t[b][h][n][d'] = x[b,n,:] @ W[h]   (3-pass split MFMA, fp32 acc, stored as hi/lo bf16)
__global__ __launch_bounds__(256) void k_t(
    const unsigned short* __restrict__ xh, const unsigned short* __restrict__ xl,
    const unsigned short* __restrict__ wh, const unsigned short* __restrict__ wl,
    unsigned short* __restrict__ th, unsigned short* __restrict__ tl) {
  const int wg = blockIdx.x;        // 2048 = b*h*(1024/32)
  const int mt = wg & 31;
  const int h  = (wg >> 5) & 7;
  const int b  = wg >> 8;
  const int wave = threadIdx.x >> 6;
  const int lane = threadIdx.x & 63;
  const int lr = lane & 15, lg = lane >> 4;

  f32x4 acc[2][4];
  const f32x4 z = {0.f, 0.f, 0.f, 0.f};
#pragma unroll
  for (int mi = 0; mi < 2; ++mi)
#pragma unroll
    for (int nt = 0; nt < 4; ++nt) acc[mi][nt] = z;

  for (int ks = 0; ks < 8; ++ks) {
    bf16x8 ahv[2], alv[2];
#pragma unroll
    for (int mi = 0; mi < 2; ++mi) {
      const size_t aoff = ((size_t)(b * 1024 + mt * 32 + mi * 16 + lr)) * 256 + ks * 32 + lg * 8;
      ahv[mi] = *(const bf16x8*)(xh + aoff);
      alv[mi] = *(const bf16x8*)(xl + aoff);
    }
#pragma unroll
    for (int nt = 0; nt < 4; ++nt) {
      const int dc = wave * 64 + nt * 16 + lr;
      const size_t boff = ((size_t)(h * 256 + dc)) * 256 + ks * 32 + lg * 8;
      bf16x8 bh = *(const bf16x8*)(wh + boff);
      bf16x8 bl = *(const bf16x8*)(wl + boff);
#pragma unroll
      for (int mi = 0; mi < 2; ++mi) {
        acc[mi][nt] = MFMA(ahv[mi], bh, acc[mi][nt]);
        acc[mi][nt] = MFMA(ahv[mi], bl, acc[mi][nt]);
        acc[mi][nt] = MFMA(alv[mi], bh, acc[mi][nt]);
      }
    }
  }
#pragma unroll
  for (int mi = 0; mi < 2; ++mi)
#pragma unroll
    for (int nt = 0; nt < 4; ++nt)
#pragma unroll
      for (int r = 0; r < 4; ++r) {
        const int row = mt * 32 + mi * 16 + lg * 4 + r;
        const int dc  = wave * 64 + nt * 16 + lr;
        const float v = acc[mi][nt][r];
        const size_t idx = ((size_t)((b * 8 + h) * 1024 + row)) * 256 + dc;
        const unsigned short hi = f32_bf16(v);
        th[idx] = hi;
        tl[idx] = f32_bf16(v - bf16_f32(hi));
      }
}

// ---------------------------------------------------------------------------
// Attention per (b, h, 16-q-row tile): S in LDS (XOR-swizzled), full-row softmax, PV.
__global__ __launch_bounds__(256) void k_attn(
    const unsigned short* __restrict__ th, const unsigned short* __restrict__ tl,
    const unsigned short* __restrict__ mh, const unsigned short* __restrict__ ml,
    const unsigned short* __restrict__ vt, unsigned short* __restrict__ ob) {
  __shared__ float S[16 * 1024];   // 64 KiB; addr(r,c) = r*1024 + (c ^ ((r&7)<<2))
  const int wg = blockIdx.x;       // 4096 = b*h*(1024/16)
  const int qt = wg & 63;
  const int h  = (wg >> 6) & 7;
  const int b  = wg >> 9;
  const int wave = threadIdx.x >> 6;
  const int lane = threadIdx.x & 63;
  const int lr = lane & 15, lg = lane >> 4;

  // ---- phase 1: S = t-tile @ m^T (3-pass split). Wave w owns s-cols [w*256, w*256+256).
  f32x4 acc[16];
  const f32x4 z = {0.f, 0.f, 0.f, 0.f};
#pragma unroll
  for (int i = 0; i < 16; ++i) acc[i] = z;

  const size_t trow = ((size_t)((b * 8 + h) * 1024 + qt * 16 + lr)) * 256;
  const size_t mbas = ((size_t)(b * 1024)) * 256;
  for (int ks = 0; ks < 8; ++ks) {
    const size_t aoff = trow + ks * 32 + lg * 8;
    bf16x8 ah = *(const bf16x8*)(th + aoff);
    bf16x8 al = *(const bf16x8*)(tl + aoff);
#pragma unroll
    for (int nt = 0; nt < 16; ++nt) {
      const int s = wave * 256 + nt * 16 + lr;
      const size_t boff = mbas + (size_t)s * 256 + ks * 32 + lg * 8;
      bf16x8 bh = *(const bf16x8*)(mh + boff);
      bf16x8 bl = *(const bf16x8*)(ml + boff);
      acc[nt] = MFMA(ah, bh, acc[nt]);
      acc[nt] = MFMA(ah, bl, acc[nt]);
      acc[nt] = MFMA(al, bh, acc[nt]);
    }
  }
#pragma unroll
  for (int nt = 0; nt < 16; ++nt) {
    const int c = wave * 256 + nt * 16 + lr;
#pragma unroll
    for (int r = 0; r < 4; ++r) {
      const int row = lg * 4 + r;
      S[row * 1024 + (c ^ ((row & 7) << 2))] = acc[nt][r];
    }
  }
  __syncthreads();

  // ---- phase 2: softmax over s (normalized P stored back). Wave w owns rows [w*4, w*4+4).
#pragma unroll
  for (int rr = 0; rr < 4; ++rr) {
    const int row = wave * 4 + rr;
    const int swz = (row & 7) << 2;
    float p[16];
    float mx = -3.0e38f;
#pragma unroll
    for (int it = 0; it < 16; ++it) {
      p[it] = S[row * 1024 + ((it * 64 + lane) ^ swz)];
      mx = fmaxf(mx, p[it]);
    }
#pragma unroll
    for (int off = 32; off > 0; off >>= 1) mx = fmaxf(mx, __shfl_xor(mx, off));
    float sum = 0.0f;
#pragma unroll
    for (int it = 0; it < 16; ++it) {
      p[it] = expf((p[it] - mx) * 0.0625f);   // scale 1/sqrt(256)
      sum += p[it];
    }
#pragma unroll
    for (int off = 32; off > 0; off >>= 1) sum += __shfl_xor(sum, off);
    const float inv = 1.0f / sum;
#pragma unroll
    for (int it = 0; it < 16; ++it)
      S[row * 1024 + ((it * 64 + lane) ^ swz)] = p[it] * inv;
  }
  __syncthreads();

  // ---- phase 3: O = P @ V. Wave w owns v-cols [w*64, w*64+64).
  f32x4 oacc[4];
#pragma unroll
  for (int i = 0; i < 4; ++i) oacc[i] = z;
  const size_t vbase = (size_t)b * 256 * 1024;
  const int aswz = (lr & 7) << 2;
  for (int ks = 0; ks < 32; ++ks) {
    const int cbase = ks * 32 + lg * 8;
    const f32x4 p0 = *(const f32x4*)&S[lr * 1024 + ((cbase)     ^ aswz)];
    const f32x4 p1 = *(const f32x4*)&S[lr * 1024 + ((cbase + 4) ^ aswz)];
    bf16x8 af;
#pragma unroll
    for (int j = 0; j < 4; ++j) {
      af[j]     = (short)f32_bf16(p0[j]);
      af[j + 4] = (short)f32_bf16(p1[j]);
    }
#pragma unroll
    for (int nt = 0; nt < 4; ++nt) {
      const int vc = wave * 64 + nt * 16 + lr;
      const size_t boff = vbase + (size_t)vc * 1024 + cbase;
      bf16x8 bv = *(const bf16x8*)(vt + boff);
      oacc[nt] = MFMA(af, bv, oacc[nt]);
    }
  }
#pragma unroll
  for (int nt = 0; nt < 4; ++nt) {
    const int vc = wave * 64 + nt * 16 + lr;
#pragma unroll
    for (int r = 0; r < 4; ++r) {
      const int n = qt * 16 + lg * 4 + r;
      ob[(((size_t)(b * 1024 + n)) * 8 + h) * 256 + vc] = f32_bf16(oacc[nt][r]);
    }
  }
}

// ---------------------------------------------------------------------------
// out[bn][d] = o[bn][hv] @ OpB[d][hv]^T   (M=8192, K=2048, N=256, bf16 MFMA, fp32 out)
__global__ __launch_bounds__(256) void k_out(
    const unsigned short* __restrict__ ob, const unsigned short* __restrict__ opb,
    float* __restrict__ out) {
  const int wg = blockIdx.x;        // 256 = 8192/32
  const int wave = threadIdx.x >> 6;
  const int lane = threadIdx.x & 63;
  const int lr = lane & 15, lg = lane >> 4;

  f32x4 acc[2][4];
  const f32x4 z = {0.f, 0.f, 0.f, 0.f};
#pragma unroll
  for (int mi = 0; mi < 2; ++mi)
#pragma unroll
    for (int nt = 0; nt < 4; ++nt) acc[mi][nt] = z;

  for (int ks = 0; ks < 64; ++ks) {
    bf16x8 av[2];
#pragma unroll
    for (int mi = 0; mi < 2; ++mi) {
      const size_t aoff = ((size_t)(wg * 32 + mi * 16 + lr)) * 2048 + ks * 32 + lg * 8;
      av[mi] = *(const bf16x8*)(ob + aoff);
    }
#pragma unroll
    for (int nt = 0; nt < 4; ++nt) {
      const int dc = wave * 64 + nt * 16 + lr;
      const size_t boff = ((size_t)dc) * 2048 + ks * 32 + lg * 8;
      bf16x8 bv = *(const bf16x8*)(opb + boff);
#pragma unroll
      for (int mi = 0; mi < 2; ++mi)
        acc[mi][nt] = MFMA(av[mi], bv, acc[mi][nt]);
    }
  }
#pragma unroll
  for (int mi = 0; mi < 2; ++mi)
#pragma unroll
    for (int nt = 0; nt < 4; ++nt)
#pragma unroll
      for (int r = 0; r < 4; ++r) {
        const int row = wg * 32 + mi * 16 + lg * 4 + r;
        const int dc  = wave * 64 + nt * 16 + lr;
        out[(size_t)row * 256 + dc] = acc[mi][nt][r];
      }
}

// ---------------------------------------------------------------------------
extern "C" void kernel_launch(void* const* d_in, const int* in_sizes, int n_in,
                              void* d_out, int out_size, void* d_ws, size_t ws_size,
                              hipStream_t stream) {
  const float* x  = (const float*)d_in[0];
  const float* m  = (const float*)d_in[1];
  const float* qp = (const float*)d_in[2];
  const float* kp = (const float*)d_in[3];
  const float* vp = (const float*)d_in[4];
  const float* op = (const float*)d_in[5];
  float* out = (float*)d_out;

  unsigned short* xh  = (unsigned short*)d_ws;            // [8][1024][256]
  unsigned short* xl  = xh  + 2097152;
  unsigned short* mh  = xl  + 2097152;                    // [8][1024][256]
  unsigned short* ml  = mh  + 2097152;
  unsigned short* wh  = ml  + 2097152;                    // [8][256][256] (d' major)
  unsigned short* wl  = wh  + 524288;
  unsigned short* opb = wl  + 524288;                     // [256][2048]
  unsigned short* vt  = opb + 524288;                     // [8][256][1024] (v major)
  unsigned short* th  = vt  + 2097152;                    // [8][8][1024][256]
  unsigned short* tl  = th  + 16777216;
  unsigned short* ob  = tl  + 16777216;                   // [8][1024][8][256]
  // total: ~125 MB of d_ws

  k_prep<<<2048, 256, 0, stream>>>(x, m, op, xh, xl, mh, ml, opb);
  k_w   <<<2048, 256, 0, stream>>>(qp, kp, wh, wl);
  k_v   <<<8192, 256, 0, stream>>>(m, vp, vt);
  k_t   <<<2048, 256, 0, stream>>>(xh, xl, wh, wl, th, tl);
  k_attn<<<4096, 256, 0, stream>>>(th, tl, mh, ml, vt, ob);
  k_out <<<256,  256, 0, stream>>>(ob, opb, out);
}

// Round 2
// 673.881 us; speedup vs baseline: 1.6111x; 1.6111x over previous
//
#include <hip/hip_runtime.h>
#include <math.h>

// Multi-query attention, MI355X gfx950.
// b=8, n=s=1024, d=k=v=256, h=8.
// Split-bf16 (hi/lo) 3-pass MFMA for the pre-softmax chain (fp32-accurate logits);
// plain bf16 MFMA post-softmax. k_attn: flash-style online softmax, swapped QK^T,
// K staged in LDS (global_load_lds, XOR-swizzled, double-buffered, counted vmcnt).

typedef short bf16x8 __attribute__((ext_vector_type(8)));
typedef float f32x4  __attribute__((ext_vector_type(4)));

#define MFMA(a, b, c) __builtin_amdgcn_mfma_f32_16x16x32_bf16((a), (b), (c), 0, 0, 0)

typedef __attribute__((address_space(3))) unsigned int lds_u32_t;
typedef __attribute__((address_space(1))) const unsigned int glb_u32_t;

__device__ __forceinline__ unsigned short f32_bf16(float f) {
  unsigned u = __float_as_uint(f);
  u += 0x7FFFu + ((u >> 16) & 1u);   // RNE
  return (unsigned short)(u >> 16);
}
__device__ __forceinline__ float bf16_f32(unsigned short h) {
  return __uint_as_float(((unsigned)h) << 16);
}

// ---------------------------------------------------------------------------
// Prep: split x,m into bf16 hi/lo; convert output_proj to bf16.
__global__ void k_prep(const float* __restrict__ x, const float* __restrict__ m,
                       const float* __restrict__ op,
                       unsigned short* __restrict__ xh, unsigned short* __restrict__ xl,
                       unsigned short* __restrict__ mh, unsigned short* __restrict__ ml,
                       unsigned short* __restrict__ opb) {
  const int tid = blockIdx.x * blockDim.x + threadIdx.x;
  const int stride = gridDim.x * blockDim.x;
  for (int i = tid; i < 2097152; i += stride) {
    float v = x[i];
    unsigned short h = f32_bf16(v);
    xh[i] = h; xl[i] = f32_bf16(v - bf16_f32(h));
    float w = m[i];
    unsigned short h2 = f32_bf16(w);
    mh[i] = h2; ml[i] = f32_bf16(w - bf16_f32(h2));
  }
  for (int i = tid; i < 524288; i += stride) opb[i] = f32_bf16(op[i]);
}

// ---------------------------------------------------------------------------
// W[h][d'][d] = sum_k Qp[h,d,k]*Kp[d',k]  (fp32, then hi/lo split), stored [d'][d].
__global__ void k_w(const float* __restrict__ qp, const float* __restrict__ kp,
                    unsigned short* __restrict__ wh, unsigned short* __restrict__ wl) {
  const int t = blockIdx.x * 256 + threadIdx.x;   // 524288 threads
  const int i = t & 255;          // d   (inner)
  const int j = (t >> 8) & 255;   // d'
  const int h = t >> 16;
  const float* qrow = qp + ((size_t)(h * 256 + i)) * 256;
  const float* krow = kp + (size_t)j * 256;
  float acc = 0.0f;
  for (int k = 0; k < 256; ++k) acc += qrow[k] * krow[k];
  const unsigned short hi = f32_bf16(acc);
  wh[t] = hi;
  wl[t] = f32_bf16(acc - bf16_f32(hi));
}

// ---------------------------------------------------------------------------
// v = m @ value_proj, stored TRANSPOSED: Vt[b][vc][s] (bf16).
__global__ void k_v(const float* __restrict__ m, const float* __restrict__ vp,
                    unsigned short* __restrict__ vt) {
  const int t = blockIdx.x * 256 + threadIdx.x;   // 2097152 threads
  const int vc = t & 255;
  const int s  = (t >> 8) & 1023;
  const int b  = t >> 18;
  const float* mrow = m + ((size_t)(b * 1024 + s)) * 256;
  float acc = 0.0f;
  for (int d = 0; d < 256; ++d) acc += mrow[d] * vp[d * 256 + vc];
  vt[((size_t)(b * 256 + vc)) * 1024 + s] = f32_bf16(acc);
}

// ---------------------------------------------------------------------------
// t[b][h][n][d'] = x[b,n,:] @ W[h]  (3-pass split MFMA, batched loads)
__global__ __launch_bounds__(256) void k_t(
    const unsigned short* __restrict__ xh, const unsigned short* __restrict__ xl,
    const unsigned short* __restrict__ wh, const unsigned short* __restrict__ wl,
    unsigned short* __restrict__ th, unsigned short* __restrict__ tl) {
  const int wg = blockIdx.x;        // 2048 = b*h*(1024/32)
  const int mt = wg & 31;
  const int h  = (wg >> 5) & 7;
  const int b  = wg >> 8;
  const int wave = threadIdx.x >> 6;
  const int lane = threadIdx.x & 63;
  const int lr = lane & 15, lg = lane >> 4;

  f32x4 acc[2][4];
  const f32x4 z = {0.f, 0.f, 0.f, 0.f};
#pragma unroll
  for (int mi = 0; mi < 2; ++mi)
#pragma unroll
    for (int nt = 0; nt < 4; ++nt) acc[mi][nt] = z;

  for (int ks = 0; ks < 8; ++ks) {
    bf16x8 ahv[2], alv[2], bh4[4], bl4[4];
#pragma unroll
    for (int mi = 0; mi < 2; ++mi) {
      const size_t aoff = ((size_t)(b * 1024 + mt * 32 + mi * 16 + lr)) * 256 + ks * 32 + lg * 8;
      ahv[mi] = *(const bf16x8*)(xh + aoff);
      alv[mi] = *(const bf16x8*)(xl + aoff);
    }
#pragma unroll
    for (int nt = 0; nt < 4; ++nt) {
      const int dc = wave * 64 + nt * 16 + lr;
      const size_t boff = ((size_t)(h * 256 + dc)) * 256 + ks * 32 + lg * 8;
      bh4[nt] = *(const bf16x8*)(wh + boff);
      bl4[nt] = *(const bf16x8*)(wl + boff);
    }
#pragma unroll
    for (int nt = 0; nt < 4; ++nt)
#pragma unroll
      for (int mi = 0; mi < 2; ++mi) {
        acc[mi][nt] = MFMA(ahv[mi], bh4[nt], acc[mi][nt]);
        acc[mi][nt] = MFMA(ahv[mi], bl4[nt], acc[mi][nt]);
        acc[mi][nt] = MFMA(alv[mi], bh4[nt], acc[mi][nt]);
      }
  }
#pragma unroll
  for (int mi = 0; mi < 2; ++mi)
#pragma unroll
    for (int nt = 0; nt < 4; ++nt)
#pragma unroll
      for (int r = 0; r < 4; ++r) {
        const int row = mt * 32 + mi * 16 + lg * 4 + r;
        const int dc  = wave * 64 + nt * 16 + lr;
        const float v = acc[mi][nt][r];
        const size_t idx = ((size_t)((b * 8 + h) * 1024 + row)) * 256 + dc;
        const unsigned short hi = f32_bf16(v);
        th[idx] = hi;
        tl[idx] = f32_bf16(v - bf16_f32(hi));
      }
}

// ---------------------------------------------------------------------------
// Flash attention per (b, h, 128-q-row tile). 8 waves, each owns 16 q-rows.
// Swapped QK^T: S^T = K_block @ t^T (t in regs as B-operand). Online softmax
// fully in-register. K staged in LDS (double-buffered, XOR-swizzled source).
// V read from L2 (contiguous in vt).
__global__ __launch_bounds__(512, 2) void k_attn(
    const unsigned short* __restrict__ th, const unsigned short* __restrict__ tl,
    const unsigned short* __restrict__ mh, const unsigned short* __restrict__ ml,
    const unsigned short* __restrict__ vt, unsigned short* __restrict__ ob) {
  __shared__ __align__(16) unsigned short KH[2][32 * 256];
  __shared__ __align__(16) unsigned short KL[2][32 * 256];

  const int wg0 = blockIdx.x;
  const int wg = (wg0 & 7) * 64 + (wg0 >> 3);   // XCD swizzle: 512 = 8*64 exact
  const int qt = wg & 7;
  const int h  = (wg >> 3) & 7;
  const int b  = wg >> 6;
  const int wv = threadIdx.x >> 6;
  const int lane = threadIdx.x & 63;
  const int lr = lane & 15, lg = lane >> 4;

  // Hoist t (B-operand for swapped QK^T): B[k=d][n=q] = t[q][d]; q = lr.
  const size_t trow = ((size_t)((b * 8 + h) * 1024 + qt * 128 + wv * 16 + lr)) * 256;
  bf16x8 Th[8], Tl[8];
#pragma unroll
  for (int d = 0; d < 8; ++d) {
    Th[d] = *(const bf16x8*)(th + trow + d * 32 + lg * 8);
    Tl[d] = *(const bf16x8*)(tl + trow + d * 32 + lg * 8);
  }

  const size_t mbase = (size_t)b * 1024 * 256;
  const size_t vbase = (size_t)b * 256 * 1024;

  // Stage K-block (32 s x 256 d, hi+lo) into LDS buffer bi.
  // LDS linear dest; SOURCE pre-swizzled: 16B-unit u_phys holds global unit
  // u_phys ^ (s&7). 4 global_load_lds per wave per call.
  auto stage = [&](int blk, int bi) {
#pragma unroll
    for (int i = 0; i < 2; ++i) {
      const int U = wv * 128 + i * 64 + lane;
      const int s_loc = U >> 5, u_phys = U & 31;
      const int u_log = u_phys ^ (s_loc & 7);
      const size_t soff = mbase + ((size_t)(blk * 32 + s_loc)) * 256 + u_log * 8;
      const int dstb = (wv * 128 + i * 64) * 8;   // wave-uniform short index
      __builtin_amdgcn_global_load_lds((glb_u32_t*)(mh + soff), (lds_u32_t*)&KH[bi][dstb], 16, 0, 0);
      __builtin_amdgcn_global_load_lds((glb_u32_t*)(ml + soff), (lds_u32_t*)&KL[bi][dstb], 16, 0, 0);
    }
  };

  f32x4 Oacc[16];
  const f32x4 z = {0.f, 0.f, 0.f, 0.f};
#pragma unroll
  for (int i = 0; i < 16; ++i) Oacc[i] = z;
  float mrun = -1e30f, lrun = 0.0f;
  const float C16 = 0.0901679993f;   // 1/(16*ln2)

  stage(0, 0);
  stage(1, 1);
  asm volatile("s_waitcnt vmcnt(4)" ::: "memory");   // stage(0) landed
  __builtin_amdgcn_s_barrier();

  int cur = 0;
  for (int blk = 0; blk < 32; ++blk) {
    // ---- QK^T (swapped): S^T frags, rows s = ntS*16+lr, cols q = lr-indexed in B
    f32x4 S0 = z, S1 = z;
#pragma unroll
    for (int d = 0; d < 8; ++d) {
      const int u0 = ((d * 4 + lg) ^ (lr & 7)) * 8;
      const bf16x8 a0h = *(const bf16x8*)&KH[cur][lr * 256 + u0];
      const bf16x8 a0l = *(const bf16x8*)&KL[cur][lr * 256 + u0];
      const bf16x8 a1h = *(const bf16x8*)&KH[cur][(16 + lr) * 256 + u0];
      const bf16x8 a1l = *(const bf16x8*)&KL[cur][(16 + lr) * 256 + u0];
      S0 = MFMA(a0h, Th[d], S0);
      S1 = MFMA(a1h, Th[d], S1);
      S0 = MFMA(a0l, Th[d], S0);
      S1 = MFMA(a1l, Th[d], S1);
      S0 = MFMA(a0h, Tl[d], S0);
      S1 = MFMA(a1h, Tl[d], S1);
    }

    // ---- V loads early (L2), consumed after softmax
    bf16x8 Vf[16];
#pragma unroll
    for (int nt = 0; nt < 16; ++nt)
      Vf[nt] = *(const bf16x8*)(vt + vbase + ((size_t)(nt * 16 + lr)) * 1024 + blk * 32 + lg * 8);

    // ---- online softmax, q = lr domain; lane holds 8 of 32 s-values of its row
    float bm = fmaxf(fmaxf(fmaxf(S0[0], S0[1]), fmaxf(S0[2], S0[3])),
                     fmaxf(fmaxf(S1[0], S1[1]), fmaxf(S1[2], S1[3])));
    bm = fmaxf(bm, __shfl_xor(bm, 16));
    bm = fmaxf(bm, __shfl_xor(bm, 32));
    if (!__all(bm - mrun <= 128.0f)) {          // defer-max: THR = 8 nats
      const float mnew = fmaxf(mrun, bm);
      const float sc = exp2f((mrun - mnew) * C16);
      const float s0 = __shfl(sc, lg * 4 + 0);  // to O's r-domain (q = lg*4+r)
      const float s1 = __shfl(sc, lg * 4 + 1);
      const float s2 = __shfl(sc, lg * 4 + 2);
      const float s3 = __shfl(sc, lg * 4 + 3);
#pragma unroll
      for (int nt = 0; nt < 16; ++nt) {
        Oacc[nt][0] *= s0; Oacc[nt][1] *= s1; Oacc[nt][2] *= s2; Oacc[nt][3] *= s3;
      }
      lrun *= sc;
      mrun = mnew;
    }
    float p[2][4];
#pragma unroll
    for (int r = 0; r < 4; ++r) {
      p[0][r] = exp2f((S0[r] - mrun) * C16);
      p[1][r] = exp2f((S1[r] - mrun) * C16);
    }
    float rs = ((p[0][0] + p[0][1]) + (p[0][2] + p[0][3])) +
               ((p[1][0] + p[1][1]) + (p[1][2] + p[1][3]));
    rs += __shfl_xor(rs, 16);
    rs += __shfl_xor(rs, 32);
    lrun += rs;

    // ---- pack P to bf16 pairs and redistribute to PV A-fragment layout
    // D[nt][h] = pack(p[nt][2h], p[nt][2h+1]); target lane (lr,lg) A-dword d
    // comes from lane lg' = 2*(lg&1) + (d>>1), content D[lg>>1][d&1].
    int D00, D01, D10, D11;
    asm("v_cvt_pk_bf16_f32 %0, %1, %2" : "=v"(D00) : "v"(p[0][0]), "v"(p[0][1]));
    asm("v_cvt_pk_bf16_f32 %0, %1, %2" : "=v"(D01) : "v"(p[0][2]), "v"(p[0][3]));
    asm("v_cvt_pk_bf16_f32 %0, %1, %2" : "=v"(D10) : "v"(p[1][0]), "v"(p[1][1]));
    asm("v_cvt_pk_bf16_f32 %0, %1, %2" : "=v"(D11) : "v"(p[1][2]), "v"(p[1][3]));
    const bool hi2 = (lg & 2) != 0;
    const bool b1  = (lg & 1) != 0;
    const int own0 = hi2 ? D10 : D00;
    const int own1 = hi2 ? D11 : D01;
    const int ant0 = hi2 ? D00 : D10;
    const int ant1 = hi2 ? D01 : D11;
    const int X0 = __shfl_xor(own0, 16);
    const int X1 = __shfl_xor(own1, 16);
    const int W0 = __shfl_xor(ant0, 32);
    const int W1 = __shfl_xor(ant1, 32);
    const int Y0 = __shfl_xor(W0, 16);
    const int Y1 = __shfl_xor(W1, 16);
    const int F0 = hi2 ? (b1 ? X0 : W0) : (b1 ? Y0 : own0);
    const int F1 = hi2 ? (b1 ? X1 : W1) : (b1 ? Y1 : own1);
    const int G0 = hi2 ? (b1 ? own0 : Y0) : (b1 ? W0 : X0);
    const int G1 = hi2 ? (b1 ? own1 : Y1) : (b1 ? W1 : X1);
    union { int u[4]; bf16x8 v; } pa;
    pa.u[0] = F0; pa.u[1] = F1; pa.u[2] = G0; pa.u[3] = G1;

    // ---- PV: O[q][vc] += P @ V_block
#pragma unroll
    for (int nt = 0; nt < 16; ++nt)
      Oacc[nt] = MFMA(pa.v, Vf[nt], Oacc[nt]);

    // ---- pipeline maintenance (counted vmcnt, raw barriers)
    __builtin_amdgcn_s_barrier();               // all waves done reading buf[cur]
    if (blk + 2 < 32) {
      stage(blk + 2, cur);
      asm volatile("s_waitcnt vmcnt(4)" ::: "memory");  // stage(blk+1) landed
    } else {
      asm volatile("s_waitcnt vmcnt(0)" ::: "memory");
    }
    __builtin_amdgcn_s_barrier();               // buf[cur^1] ready for all
    cur ^= 1;
  }

  // ---- epilogue: normalize, convert, store (O rows q = lg*4+r)
  const float inv = 1.0f / lrun;                 // q = lr domain
  const float i0 = __shfl(inv, lg * 4 + 0);
  const float i1 = __shfl(inv, lg * 4 + 1);
  const float i2 = __shfl(inv, lg * 4 + 2);
  const float i3 = __shfl(inv, lg * 4 + 3);
  const int qg = qt * 128 + wv * 16 + lg * 4;
  const size_t obase = ((size_t)(b * 1024 + qg) * 8 + h) * 256 + lr;
#pragma unroll
  for (int nt = 0; nt < 16; ++nt) {
    ob[obase + 0 * 2048 + nt * 16] = f32_bf16(Oacc[nt][0] * i0);
    ob[obase + 1 * 2048 + nt * 16] = f32_bf16(Oacc[nt][1] * i1);
    ob[obase + 2 * 2048 + nt * 16] = f32_bf16(Oacc[nt][2] * i2);
    ob[obase + 3 * 2048 + nt * 16] = f32_bf16(Oacc[nt][3] * i3);
  }
}

// ---------------------------------------------------------------------------
// out[bn][d] = o[bn][hv] @ OpB[d][hv]^T  (M=8192, K=2048, N=256, batched loads)
__global__ __launch_bounds__(256) void k_out(
    const unsigned short* __restrict__ ob, const unsigned short* __restrict__ opb,
    float* __restrict__ out) {
  const int wg = blockIdx.x;        // 256 = 8192/32
  const int wave = threadIdx.x >> 6;
  const int lane = threadIdx.x & 63;
  const int lr = lane & 15, lg = lane >> 4;

  f32x4 acc[2][4];
  const f32x4 z = {0.f, 0.f, 0.f, 0.f};
#pragma unroll
  for (int mi = 0; mi < 2; ++mi)
#pragma unroll
    for (int nt = 0; nt < 4; ++nt) acc[mi][nt] = z;

  for (int ks = 0; ks < 64; ++ks) {
    bf16x8 av[2], bv[4];
#pragma unroll
    for (int mi = 0; mi < 2; ++mi) {
      const size_t aoff = ((size_t)(wg * 32 + mi * 16 + lr)) * 2048 + ks * 32 + lg * 8;
      av[mi] = *(const bf16x8*)(ob + aoff);
    }
#pragma unroll
    for (int nt = 0; nt < 4; ++nt) {
      const int dc = wave * 64 + nt * 16 + lr;
      bv[nt] = *(const bf16x8*)(opb + ((size_t)dc) * 2048 + ks * 32 + lg * 8);
    }
#pragma unroll
    for (int nt = 0; nt < 4; ++nt)
#pragma unroll
      for (int mi = 0; mi < 2; ++mi)
        acc[mi][nt] = MFMA(av[mi], bv[nt], acc[mi][nt]);
  }
#pragma unroll
  for (int mi = 0; mi < 2; ++mi)
#pragma unroll
    for (int nt = 0; nt < 4; ++nt)
#pragma unroll
      for (int r = 0; r < 4; ++r) {
        const int row = wg * 32 + mi * 16 + lg * 4 + r;
        const int dc  = wave * 64 + nt * 16 + lr;
        out[(size_t)row * 256 + dc] = acc[mi][nt][r];
      }
}

// ---------------------------------------------------------------------------
extern "C" void kernel_launch(void* const* d_in, const int* in_sizes, int n_in,
                              void* d_out, int out_size, void* d_ws, size_t ws_size,
                              hipStream_t stream) {
  const float* x  = (const float*)d_in[0];
  const float* m  = (const float*)d_in[1];
  const float* qp = (const float*)d_in[2];
  const float* kp = (const float*)d_in[3];
  const float* vp = (const float*)d_in[4];
  const float* op = (const float*)d_in[5];
  float* out = (float*)d_out;

  unsigned short* xh  = (unsigned short*)d_ws;            // [8][1024][256]
  unsigned short* xl  = xh  + 2097152;
  unsigned short* mh  = xl  + 2097152;                    // [8][1024][256]
  unsigned short* ml  = mh  + 2097152;
  unsigned short* wh  = ml  + 2097152;                    // [8][256][256] (d' major)
  unsigned short* wl  = wh  + 524288;
  unsigned short* opb = wl  + 524288;                     // [256][2048]
  unsigned short* vt  = opb + 524288;                     // [8][256][1024] (v major)
  unsigned short* th  = vt  + 2097152;                    // [8][8][1024][256]
  unsigned short* tl  = th  + 16777216;
  unsigned short* ob  = tl  + 16777216;                   // [8][1024][8][256]

  k_prep<<<2048, 256, 0, stream>>>(x, m, op, xh, xl, mh, ml, opb);
  k_w   <<<2048, 256, 0, stream>>>(qp, kp, wh, wl);
  k_v   <<<8192, 256, 0, stream>>>(m, vp, vt);
  k_t   <<<2048, 256, 0, stream>>>(xh, xl, wh, wl, th, tl);
  k_attn<<<512,  512, 0, stream>>>(th, tl, mh, ml, vt, ob);
  k_out <<<256,  256, 0, stream>>>(ob, opb, out);
}

// Round 3
// 603.691 us; speedup vs baseline: 1.7984x; 1.1163x over previous
//
#include <hip/hip_runtime.h>
#include <math.h>

// Multi-query attention, MI355X gfx950.
// b=8, n=s=1024, d=k=v=256, h=8.
// Split-bf16 (hi/lo) 3-pass MFMA pre-softmax; plain bf16 MFMA post-softmax.
// k_attn: flash online softmax, swapped QK^T, K staged via global_load_lds
// (XOR-swizzled source), single barrier per block, pipelined stage/V-loads.

typedef short bf16x8 __attribute__((ext_vector_type(8)));
typedef float f32x4  __attribute__((ext_vector_type(4)));

#define MFMA(a, b, c) __builtin_amdgcn_mfma_f32_16x16x32_bf16((a), (b), (c), 0, 0, 0)

typedef __attribute__((address_space(3))) unsigned int lds_u32_t;
typedef __attribute__((address_space(1))) const unsigned int glb_u32_t;

__device__ __forceinline__ unsigned short f32_bf16(float f) {
  unsigned u = __float_as_uint(f);
  u += 0x7FFFu + ((u >> 16) & 1u);   // RNE
  return (unsigned short)(u >> 16);
}
__device__ __forceinline__ float bf16_f32(unsigned short h) {
  return __uint_as_float(((unsigned)h) << 16);
}

// ---------------------------------------------------------------------------
// Prep: split x,m,qp,kp into bf16 hi/lo; output_proj -> bf16; vp -> vp^T bf16.
__global__ void k_prep(const float* __restrict__ x, const float* __restrict__ m,
                       const float* __restrict__ op, const float* __restrict__ qp,
                       const float* __restrict__ kp, const float* __restrict__ vp,
                       unsigned short* __restrict__ xh, unsigned short* __restrict__ xl,
                       unsigned short* __restrict__ mh, unsigned short* __restrict__ ml,
                       unsigned short* __restrict__ opb,
                       unsigned short* __restrict__ qph, unsigned short* __restrict__ qpl,
                       unsigned short* __restrict__ kph, unsigned short* __restrict__ kpl,
                       unsigned short* __restrict__ vpt) {
  const int tid = blockIdx.x * blockDim.x + threadIdx.x;
  const int stride = gridDim.x * blockDim.x;
  for (int i = tid; i < 2097152; i += stride) {
    float v = x[i];
    unsigned short h = f32_bf16(v);
    xh[i] = h; xl[i] = f32_bf16(v - bf16_f32(h));
    float w = m[i];
    unsigned short h2 = f32_bf16(w);
    mh[i] = h2; ml[i] = f32_bf16(w - bf16_f32(h2));
  }
  for (int i = tid; i < 524288; i += stride) {
    opb[i] = f32_bf16(op[i]);
    float q = qp[i];
    unsigned short h = f32_bf16(q);
    qph[i] = h; qpl[i] = f32_bf16(q - bf16_f32(h));
  }
  for (int i = tid; i < 65536; i += stride) {
    float k = kp[i];
    unsigned short h = f32_bf16(k);
    kph[i] = h; kpl[i] = f32_bf16(k - bf16_f32(h));
    const int vc = i >> 8, d = i & 255;
    vpt[i] = f32_bf16(vp[d * 256 + vc]);   // vpt[vc][d]
  }
}

// ---------------------------------------------------------------------------
// W[h][j][i] = sum_k Qp[h,i,k]*Kp[j,k]  (3-pass split MFMA, stored hi/lo).
__global__ __launch_bounds__(256) void k_w(
    const unsigned short* __restrict__ qph, const unsigned short* __restrict__ qpl,
    const unsigned short* __restrict__ kph, const unsigned short* __restrict__ kpl,
    unsigned short* __restrict__ wh, unsigned short* __restrict__ wl) {
  const int jt = blockIdx.x & 7;      // 64 WGs = 8h x 8jt
  const int h  = blockIdx.x >> 3;
  const int wave = threadIdx.x >> 6;
  const int lane = threadIdx.x & 63;
  const int lr = lane & 15, lg = lane >> 4;

  f32x4 acc[2][4];
  const f32x4 z = {0.f, 0.f, 0.f, 0.f};
#pragma unroll
  for (int mi = 0; mi < 2; ++mi)
#pragma unroll
    for (int nt = 0; nt < 4; ++nt) acc[mi][nt] = z;

  for (int ks = 0; ks < 8; ++ks) {
    bf16x8 ah[2], al[2], bh[4], bl[4];
#pragma unroll
    for (int mi = 0; mi < 2; ++mi) {
      const size_t aoff = ((size_t)(jt * 32 + mi * 16 + lr)) * 256 + ks * 32 + lg * 8;
      ah[mi] = *(const bf16x8*)(kph + aoff);
      al[mi] = *(const bf16x8*)(kpl + aoff);
    }
#pragma unroll
    for (int nt = 0; nt < 4; ++nt) {
      const size_t boff = ((size_t)(h * 256 + wave * 64 + nt * 16 + lr)) * 256 + ks * 32 + lg * 8;
      bh[nt] = *(const bf16x8*)(qph + boff);
      bl[nt] = *(const bf16x8*)(qpl + boff);
    }
#pragma unroll
    for (int nt = 0; nt < 4; ++nt)
#pragma unroll
      for (int mi = 0; mi < 2; ++mi) {
        acc[mi][nt] = MFMA(ah[mi], bh[nt], acc[mi][nt]);
        acc[mi][nt] = MFMA(ah[mi], bl[nt], acc[mi][nt]);
        acc[mi][nt] = MFMA(al[mi], bh[nt], acc[mi][nt]);
      }
  }
#pragma unroll
  for (int mi = 0; mi < 2; ++mi)
#pragma unroll
    for (int nt = 0; nt < 4; ++nt)
#pragma unroll
      for (int r = 0; r < 4; ++r) {
        const int j = jt * 32 + mi * 16 + lg * 4 + r;
        const int i = wave * 64 + nt * 16 + lr;
        const float v = acc[mi][nt][r];
        const size_t idx = ((size_t)(h * 256 + j)) * 256 + i;
        const unsigned short hi = f32_bf16(v);
        wh[idx] = hi;
        wl[idx] = f32_bf16(v - bf16_f32(hi));
      }
}

// ---------------------------------------------------------------------------
// vt[b][vc][s] = sum_d m[b,s,d]*vp[d,vc]  (1-pass bf16 MFMA; A=vpt rows vc, B=mh cols s)
__global__ __launch_bounds__(256) void k_v(
    const unsigned short* __restrict__ vpt, const unsigned short* __restrict__ mh,
    unsigned short* __restrict__ vt) {
  const int sc  = blockIdx.x & 3;     // 256 WGs = 8b x 8vct x 4sc
  const int vct = (blockIdx.x >> 2) & 7;
  const int b   = blockIdx.x >> 5;
  const int wave = threadIdx.x >> 6;
  const int lane = threadIdx.x & 63;
  const int lr = lane & 15, lg = lane >> 4;

  f32x4 acc[2][4];
  const f32x4 z = {0.f, 0.f, 0.f, 0.f};
#pragma unroll
  for (int mi = 0; mi < 2; ++mi)
#pragma unroll
    for (int nt = 0; nt < 4; ++nt) acc[mi][nt] = z;

  for (int ks = 0; ks < 8; ++ks) {
    bf16x8 av[2], bv[4];
#pragma unroll
    for (int mi = 0; mi < 2; ++mi)
      av[mi] = *(const bf16x8*)(vpt + ((size_t)(vct * 32 + mi * 16 + lr)) * 256 + ks * 32 + lg * 8);
#pragma unroll
    for (int nt = 0; nt < 4; ++nt)
      bv[nt] = *(const bf16x8*)(mh + ((size_t)(b * 1024 + sc * 256 + wave * 64 + nt * 16 + lr)) * 256 + ks * 32 + lg * 8);
#pragma unroll
    for (int nt = 0; nt < 4; ++nt)
#pragma unroll
      for (int mi = 0; mi < 2; ++mi)
        acc[mi][nt] = MFMA(av[mi], bv[nt], acc[mi][nt]);
  }
#pragma unroll
  for (int mi = 0; mi < 2; ++mi)
#pragma unroll
    for (int nt = 0; nt < 4; ++nt)
#pragma unroll
      for (int r = 0; r < 4; ++r) {
        const int vc = vct * 32 + mi * 16 + lg * 4 + r;
        const int s  = sc * 256 + wave * 64 + nt * 16 + lr;
        vt[((size_t)(b * 256 + vc)) * 1024 + s] = f32_bf16(acc[mi][nt][r]);
      }
}

// ---------------------------------------------------------------------------
// t[b][h][n][d'] = x[b,n,:] @ W[h]  (3-pass split MFMA, batched loads)
__global__ __launch_bounds__(256) void k_t(
    const unsigned short* __restrict__ xh, const unsigned short* __restrict__ xl,
    const unsigned short* __restrict__ wh, const unsigned short* __restrict__ wl,
    unsigned short* __restrict__ th, unsigned short* __restrict__ tl) {
  const int wg = blockIdx.x;        // 2048 = b*h*(1024/32)
  const int mt = wg & 31;
  const int h  = (wg >> 5) & 7;
  const int b  = wg >> 8;
  const int wave = threadIdx.x >> 6;
  const int lane = threadIdx.x & 63;
  const int lr = lane & 15, lg = lane >> 4;

  f32x4 acc[2][4];
  const f32x4 z = {0.f, 0.f, 0.f, 0.f};
#pragma unroll
  for (int mi = 0; mi < 2; ++mi)
#pragma unroll
    for (int nt = 0; nt < 4; ++nt) acc[mi][nt] = z;

  for (int ks = 0; ks < 8; ++ks) {
    bf16x8 ahv[2], alv[2], bh4[4], bl4[4];
#pragma unroll
    for (int mi = 0; mi < 2; ++mi) {
      const size_t aoff = ((size_t)(b * 1024 + mt * 32 + mi * 16 + lr)) * 256 + ks * 32 + lg * 8;
      ahv[mi] = *(const bf16x8*)(xh + aoff);
      alv[mi] = *(const bf16x8*)(xl + aoff);
    }
#pragma unroll
    for (int nt = 0; nt < 4; ++nt) {
      const int dc = wave * 64 + nt * 16 + lr;
      const size_t boff = ((size_t)(h * 256 + dc)) * 256 + ks * 32 + lg * 8;
      bh4[nt] = *(const bf16x8*)(wh + boff);
      bl4[nt] = *(const bf16x8*)(wl + boff);
    }
#pragma unroll
    for (int nt = 0; nt < 4; ++nt)
#pragma unroll
      for (int mi = 0; mi < 2; ++mi) {
        acc[mi][nt] = MFMA(ahv[mi], bh4[nt], acc[mi][nt]);
        acc[mi][nt] = MFMA(ahv[mi], bl4[nt], acc[mi][nt]);
        acc[mi][nt] = MFMA(alv[mi], bh4[nt], acc[mi][nt]);
      }
  }
#pragma unroll
  for (int mi = 0; mi < 2; ++mi)
#pragma unroll
    for (int nt = 0; nt < 4; ++nt)
#pragma unroll
      for (int r = 0; r < 4; ++r) {
        const int row = mt * 32 + mi * 16 + lg * 4 + r;
        const int dc  = wave * 64 + nt * 16 + lr;
        const float v = acc[mi][nt][r];
        const size_t idx = ((size_t)((b * 8 + h) * 1024 + row)) * 256 + dc;
        const unsigned short hi = f32_bf16(v);
        th[idx] = hi;
        tl[idx] = f32_bf16(v - bf16_f32(hi));
      }
}

// ---------------------------------------------------------------------------
// Flash attention per (b, h, 128-q-row tile). 8 waves x 16 q-rows.
// One barrier + one vmcnt(0) per 32-s block; PV+QK^T form one MFMA cluster.
__global__ __launch_bounds__(512, 2) void k_attn(
    const unsigned short* __restrict__ th, const unsigned short* __restrict__ tl,
    const unsigned short* __restrict__ mh, const unsigned short* __restrict__ ml,
    const unsigned short* __restrict__ vt, unsigned short* __restrict__ ob) {
  __shared__ __align__(16) unsigned short KH[2][32 * 256];
  __shared__ __align__(16) unsigned short KL[2][32 * 256];

  const int wg0 = blockIdx.x;
  const int wg = (wg0 & 7) * 64 + (wg0 >> 3);   // XCD swizzle: b = XCD id
  const int qt = wg & 7;
  const int h  = (wg >> 3) & 7;
  const int b  = wg >> 6;
  const int wv = threadIdx.x >> 6;
  const int lane = threadIdx.x & 63;
  const int lr = lane & 15, lg = lane >> 4;

  // Hoist t (B-operand for swapped QK^T): q = lr.
  const size_t trow = ((size_t)((b * 8 + h) * 1024 + qt * 128 + wv * 16 + lr)) * 256;
  bf16x8 Th[8], Tl[8];
#pragma unroll
  for (int d = 0; d < 8; ++d) {
    Th[d] = *(const bf16x8*)(th + trow + d * 32 + lg * 8);
    Tl[d] = *(const bf16x8*)(tl + trow + d * 32 + lg * 8);
  }

  const size_t mbase = (size_t)b * 1024 * 256;
  const size_t vbase = (size_t)b * 256 * 1024;

  // Stage K-block (32 s x 256 d, hi+lo). Linear LDS dest; source pre-swizzled
  // so LDS 16B-unit u holds global unit u ^ (s&7).
  auto stage = [&](int blk, int bi) {
#pragma unroll
    for (int i = 0; i < 2; ++i) {
      const int U = wv * 128 + i * 64 + lane;
      const int s_loc = U >> 5, u_phys = U & 31;
      const int u_log = u_phys ^ (s_loc & 7);
      const size_t soff = mbase + ((size_t)(blk * 32 + s_loc)) * 256 + u_log * 8;
      const int dstb = (wv * 128 + i * 64) * 8;
      __builtin_amdgcn_global_load_lds((glb_u32_t*)(mh + soff), (lds_u32_t*)&KH[bi][dstb], 16, 0, 0);
      __builtin_amdgcn_global_load_lds((glb_u32_t*)(ml + soff), (lds_u32_t*)&KL[bi][dstb], 16, 0, 0);
    }
  };

  f32x4 Oacc[16];
  const f32x4 z = {0.f, 0.f, 0.f, 0.f};
#pragma unroll
  for (int i = 0; i < 16; ++i) Oacc[i] = z;
  float mrun = -1e30f, lrun = 0.0f;
  const float C16 = 0.0901679993f;   // 1/(16*ln2)

  bf16x8 Vf[16];
  f32x4 S0 = z, S1 = z;

  // ---- prologue
  stage(0, 0);
  stage(1, 1);
#pragma unroll
  for (int nt = 0; nt < 16; ++nt)    // V(0)
    Vf[nt] = *(const bf16x8*)(vt + vbase + ((size_t)(nt * 16 + lr)) * 1024 + 0 * 32 + lg * 8);
  asm volatile("s_waitcnt vmcnt(20)" ::: "memory");   // stage(0) landed
  __builtin_amdgcn_s_barrier();

  // QK^T(0)
#pragma unroll
  for (int d = 0; d < 8; ++d) {
    const int u0 = ((d * 4 + lg) ^ (lr & 7)) * 8;
    const bf16x8 a0h = *(const bf16x8*)&KH[0][lr * 256 + u0];
    const bf16x8 a0l = *(const bf16x8*)&KL[0][lr * 256 + u0];
    const bf16x8 a1h = *(const bf16x8*)&KH[0][(16 + lr) * 256 + u0];
    const bf16x8 a1l = *(const bf16x8*)&KL[0][(16 + lr) * 256 + u0];
    S0 = MFMA(a0h, Th[d], S0);  S1 = MFMA(a1h, Th[d], S1);
    S0 = MFMA(a0l, Th[d], S0);  S1 = MFMA(a1l, Th[d], S1);
    S0 = MFMA(a0h, Tl[d], S0);  S1 = MFMA(a1h, Tl[d], S1);
  }

#pragma unroll 1
  for (int blk = 0; blk < 31; ++blk) {
    // ---- softmax on S(blk) -> pa (VALU only)
    float bm = fmaxf(fmaxf(fmaxf(S0[0], S0[1]), fmaxf(S0[2], S0[3])),
                     fmaxf(fmaxf(S1[0], S1[1]), fmaxf(S1[2], S1[3])));
    bm = fmaxf(bm, __shfl_xor(bm, 16));
    bm = fmaxf(bm, __shfl_xor(bm, 32));
    if (!__all(bm - mrun <= 128.0f)) {          // defer-max: THR = 8 nats
      const float mnew = fmaxf(mrun, bm);
      const float sc = exp2f((mrun - mnew) * C16);
      const float s0 = __shfl(sc, lg * 4 + 0);
      const float s1 = __shfl(sc, lg * 4 + 1);
      const float s2 = __shfl(sc, lg * 4 + 2);
      const float s3 = __shfl(sc, lg * 4 + 3);
#pragma unroll
      for (int nt = 0; nt < 16; ++nt) {
        Oacc[nt][0] *= s0; Oacc[nt][1] *= s1; Oacc[nt][2] *= s2; Oacc[nt][3] *= s3;
      }
      lrun *= sc;
      mrun = mnew;
    }
    float p[2][4];
#pragma unroll
    for (int r = 0; r < 4; ++r) {
      p[0][r] = exp2f((S0[r] - mrun) * C16);
      p[1][r] = exp2f((S1[r] - mrun) * C16);
    }
    float rs = ((p[0][0] + p[0][1]) + (p[0][2] + p[0][3])) +
               ((p[1][0] + p[1][1]) + (p[1][2] + p[1][3]));
    rs += __shfl_xor(rs, 16);
    rs += __shfl_xor(rs, 32);
    lrun += rs;

    int D00, D01, D10, D11;
    asm("v_cvt_pk_bf16_f32 %0, %1, %2" : "=v"(D00) : "v"(p[0][0]), "v"(p[0][1]));
    asm("v_cvt_pk_bf16_f32 %0, %1, %2" : "=v"(D01) : "v"(p[0][2]), "v"(p[0][3]));
    asm("v_cvt_pk_bf16_f32 %0, %1, %2" : "=v"(D10) : "v"(p[1][0]), "v"(p[1][1]));
    asm("v_cvt_pk_bf16_f32 %0, %1, %2" : "=v"(D11) : "v"(p[1][2]), "v"(p[1][3]));
    const bool hi2 = (lg & 2) != 0;
    const bool b1  = (lg & 1) != 0;
    const int own0 = hi2 ? D10 : D00;
    const int own1 = hi2 ? D11 : D01;
    const int ant0 = hi2 ? D00 : D10;
    const int ant1 = hi2 ? D01 : D11;
    const int X0 = __shfl_xor(own0, 16);
    const int X1 = __shfl_xor(own1, 16);
    const int W0 = __shfl_xor(ant0, 32);
    const int W1 = __shfl_xor(ant1, 32);
    const int Y0 = __shfl_xor(W0, 16);
    const int Y1 = __shfl_xor(W1, 16);
    const int F0 = hi2 ? (b1 ? X0 : W0) : (b1 ? Y0 : own0);
    const int F1 = hi2 ? (b1 ? X1 : W1) : (b1 ? Y1 : own1);
    const int G0 = hi2 ? (b1 ? own0 : Y0) : (b1 ? W0 : X0);
    const int G1 = hi2 ? (b1 ? own1 : Y1) : (b1 ? W1 : X1);
    union { int u[4]; bf16x8 v; } pa;
    pa.u[0] = F0; pa.u[1] = F1; pa.u[2] = G0; pa.u[3] = G1;

    // ---- swap point: everything staged for blk+1 must be in
    asm volatile("s_waitcnt vmcnt(0)" ::: "memory");
    __builtin_amdgcn_s_barrier();

    if (blk < 30) stage(blk + 2, blk & 1);

    // ---- PV(blk)
    __builtin_amdgcn_s_setprio(1);
#pragma unroll
    for (int nt = 0; nt < 16; ++nt)
      Oacc[nt] = MFMA(pa.v, Vf[nt], Oacc[nt]);
    __builtin_amdgcn_s_setprio(0);

    // ---- V(blk+1)
#pragma unroll
    for (int nt = 0; nt < 16; ++nt)
      Vf[nt] = *(const bf16x8*)(vt + vbase + ((size_t)(nt * 16 + lr)) * 1024 + (blk + 1) * 32 + lg * 8);

    // ---- QK^T(blk+1)
    const int nb = (blk + 1) & 1;
    S0 = z; S1 = z;
    __builtin_amdgcn_s_setprio(1);
#pragma unroll
    for (int d = 0; d < 8; ++d) {
      const int u0 = ((d * 4 + lg) ^ (lr & 7)) * 8;
      const bf16x8 a0h = *(const bf16x8*)&KH[nb][lr * 256 + u0];
      const bf16x8 a0l = *(const bf16x8*)&KL[nb][lr * 256 + u0];
      const bf16x8 a1h = *(const bf16x8*)&KH[nb][(16 + lr) * 256 + u0];
      const bf16x8 a1l = *(const bf16x8*)&KL[nb][(16 + lr) * 256 + u0];
      S0 = MFMA(a0h, Th[d], S0);  S1 = MFMA(a1h, Th[d], S1);
      S0 = MFMA(a0l, Th[d], S0);  S1 = MFMA(a1l, Th[d], S1);
      S0 = MFMA(a0h, Tl[d], S0);  S1 = MFMA(a1h, Tl[d], S1);
    }
    __builtin_amdgcn_s_setprio(0);
  }

  // ---- tail: block 31
  {
    float bm = fmaxf(fmaxf(fmaxf(S0[0], S0[1]), fmaxf(S0[2], S0[3])),
                     fmaxf(fmaxf(S1[0], S1[1]), fmaxf(S1[2], S1[3])));
    bm = fmaxf(bm, __shfl_xor(bm, 16));
    bm = fmaxf(bm, __shfl_xor(bm, 32));
    if (!__all(bm - mrun <= 128.0f)) {
      const float mnew = fmaxf(mrun, bm);
      const float sc = exp2f((mrun - mnew) * C16);
      const float s0 = __shfl(sc, lg * 4 + 0);
      const float s1 = __shfl(sc, lg * 4 + 1);
      const float s2 = __shfl(sc, lg * 4 + 2);
      const float s3 = __shfl(sc, lg * 4 + 3);
#pragma unroll
      for (int nt = 0; nt < 16; ++nt) {
        Oacc[nt][0] *= s0; Oacc[nt][1] *= s1; Oacc[nt][2] *= s2; Oacc[nt][3] *= s3;
      }
      lrun *= sc;
      mrun = mnew;
    }
    float p[2][4];
#pragma unroll
    for (int r = 0; r < 4; ++r) {
      p[0][r] = exp2f((S0[r] - mrun) * C16);
      p[1][r] = exp2f((S1[r] - mrun) * C16);
    }
    float rs = ((p[0][0] + p[0][1]) + (p[0][2] + p[0][3])) +
               ((p[1][0] + p[1][1]) + (p[1][2] + p[1][3]));
    rs += __shfl_xor(rs, 16);
    rs += __shfl_xor(rs, 32);
    lrun += rs;

    int D00, D01, D10, D11;
    asm("v_cvt_pk_bf16_f32 %0, %1, %2" : "=v"(D00) : "v"(p[0][0]), "v"(p[0][1]));
    asm("v_cvt_pk_bf16_f32 %0, %1, %2" : "=v"(D01) : "v"(p[0][2]), "v"(p[0][3]));
    asm("v_cvt_pk_bf16_f32 %0, %1, %2" : "=v"(D10) : "v"(p[1][0]), "v"(p[1][1]));
    asm("v_cvt_pk_bf16_f32 %0, %1, %2" : "=v"(D11) : "v"(p[1][2]), "v"(p[1][3]));
    const bool hi2 = (lg & 2) != 0;
    const bool b1  = (lg & 1) != 0;
    const int own0 = hi2 ? D10 : D00;
    const int own1 = hi2 ? D11 : D01;
    const int ant0 = hi2 ? D00 : D10;
    const int ant1 = hi2 ? D01 : D11;
    const int X0 = __shfl_xor(own0, 16);
    const int X1 = __shfl_xor(own1, 16);
    const int W0 = __shfl_xor(ant0, 32);
    const int W1 = __shfl_xor(ant1, 32);
    const int Y0 = __shfl_xor(W0, 16);
    const int Y1 = __shfl_xor(W1, 16);
    const int F0 = hi2 ? (b1 ? X0 : W0) : (b1 ? Y0 : own0);
    const int F1 = hi2 ? (b1 ? X1 : W1) : (b1 ? Y1 : own1);
    const int G0 = hi2 ? (b1 ? own0 : Y0) : (b1 ? W0 : X0);
    const int G1 = hi2 ? (b1 ? own1 : Y1) : (b1 ? W1 : X1);
    union { int u[4]; bf16x8 v; } pa;
    pa.u[0] = F0; pa.u[1] = F1; pa.u[2] = G0; pa.u[3] = G1;
#pragma unroll
    for (int nt = 0; nt < 16; ++nt)
      Oacc[nt] = MFMA(pa.v, Vf[nt], Oacc[nt]);
  }

  // ---- epilogue
  const float inv = 1.0f / lrun;
  const float i0 = __shfl(inv, lg * 4 + 0);
  const float i1 = __shfl(inv, lg * 4 + 1);
  const float i2 = __shfl(inv, lg * 4 + 2);
  const float i3 = __shfl(inv, lg * 4 + 3);
  const int qg = qt * 128 + wv * 16 + lg * 4;
  const size_t obase = ((size_t)(b * 1024 + qg) * 8 + h) * 256 + lr;
#pragma unroll
  for (int nt = 0; nt < 16; ++nt) {
    ob[obase + 0 * 2048 + nt * 16] = f32_bf16(Oacc[nt][0] * i0);
    ob[obase + 1 * 2048 + nt * 16] = f32_bf16(Oacc[nt][1] * i1);
    ob[obase + 2 * 2048 + nt * 16] = f32_bf16(Oacc[nt][2] * i2);
    ob[obase + 3 * 2048 + nt * 16] = f32_bf16(Oacc[nt][3] * i3);
  }
}

// ---------------------------------------------------------------------------
// out[bn][d] = o[bn][hv] @ OpB[d][hv]^T  (M=8192, K=2048, N=256)
__global__ __launch_bounds__(256) void k_out(
    const unsigned short* __restrict__ ob, const unsigned short* __restrict__ opb,
    float* __restrict__ out) {
  const int wg = blockIdx.x;        // 256 = 8192/32
  const int wave = threadIdx.x >> 6;
  const int lane = threadIdx.x & 63;
  const int lr = lane & 15, lg = lane >> 4;

  f32x4 acc[2][4];
  const f32x4 z = {0.f, 0.f, 0.f, 0.f};
#pragma unroll
  for (int mi = 0; mi < 2; ++mi)
#pragma unroll
    for (int nt = 0; nt < 4; ++nt) acc[mi][nt] = z;

  for (int ks = 0; ks < 64; ++ks) {
    bf16x8 av[2], bv[4];
#pragma unroll
    for (int mi = 0; mi < 2; ++mi) {
      const size_t aoff = ((size_t)(wg * 32 + mi * 16 + lr)) * 2048 + ks * 32 + lg * 8;
      av[mi] = *(const bf16x8*)(ob + aoff);
    }
#pragma unroll
    for (int nt = 0; nt < 4; ++nt) {
      const int dc = wave * 64 + nt * 16 + lr;
      bv[nt] = *(const bf16x8*)(opb + ((size_t)dc) * 2048 + ks * 32 + lg * 8);
    }
#pragma unroll
    for (int nt = 0; nt < 4; ++nt)
#pragma unroll
      for (int mi = 0; mi < 2; ++mi)
        acc[mi][nt] = MFMA(av[mi], bv[nt], acc[mi][nt]);
  }
#pragma unroll
  for (int mi = 0; mi < 2; ++mi)
#pragma unroll
    for (int nt = 0; nt < 4; ++nt)
#pragma unroll
      for (int r = 0; r < 4; ++r) {
        const int row = wg * 32 + mi * 16 + lg * 4 + r;
        const int dc  = wave * 64 + nt * 16 + lr;
        out[(size_t)row * 256 + dc] = acc[mi][nt][r];
      }
}

// ---------------------------------------------------------------------------
extern "C" void kernel_launch(void* const* d_in, const int* in_sizes, int n_in,
                              void* d_out, int out_size, void* d_ws, size_t ws_size,
                              hipStream_t stream) {
  const float* x  = (const float*)d_in[0];
  const float* m  = (const float*)d_in[1];
  const float* qp = (const float*)d_in[2];
  const float* kp = (const float*)d_in[3];
  const float* vp = (const float*)d_in[4];
  const float* op = (const float*)d_in[5];
  float* out = (float*)d_out;

  unsigned short* xh  = (unsigned short*)d_ws;            // [8][1024][256]
  unsigned short* xl  = xh  + 2097152;
  unsigned short* mh  = xl  + 2097152;                    // [8][1024][256]
  unsigned short* ml  = mh  + 2097152;
  unsigned short* wh  = ml  + 2097152;                    // [8][256][256] (j major)
  unsigned short* wl  = wh  + 524288;
  unsigned short* opb = wl  + 524288;                     // [256][2048]
  unsigned short* vt  = opb + 524288;                     // [8][256][1024]
  unsigned short* th  = vt  + 2097152;                    // [8][8][1024][256]
  unsigned short* tl  = th  + 16777216;
  unsigned short* ob  = tl  + 16777216;                   // [8][1024][8][256]
  unsigned short* qph = ob  + 16777216;                   // [8][256][256]
  unsigned short* qpl = qph + 524288;
  unsigned short* kph = qpl + 524288;                     // [256][256]
  unsigned short* kpl = kph + 65536;
  unsigned short* vpt = kpl + 65536;                      // [256][256]

  k_prep<<<2048, 256, 0, stream>>>(x, m, op, qp, kp, vp, xh, xl, mh, ml, opb,
                                   qph, qpl, kph, kpl, vpt);
  k_w   <<<64,   256, 0, stream>>>(qph, qpl, kph, kpl, wh, wl);
  k_v   <<<256,  256, 0, stream>>>(vpt, mh, vt);
  k_t   <<<2048, 256, 0, stream>>>(xh, xl, wh, wl, th, tl);
  k_attn<<<512,  512, 0, stream>>>(th, tl, mh, ml, vt, ob);
  k_out <<<256,  256, 0, stream>>>(ob, opb, out);
}

// Round 4
// 344.866 us; speedup vs baseline: 3.1482x; 1.7505x over previous
//
#include <hip/hip_runtime.h>
#include <math.h>

// Multi-query attention, MI355X gfx950.
// b=8, n=s=1024, d=k=v=256, h=8.
// Split-bf16 (hi/lo) 3-pass MFMA pre-softmax; plain bf16 MFMA post-softmax.
// k_attn: flash online softmax, swapped QK^T, K+V staged in LDS via
// global_load_lds (pre-swizzled sources), 1 barrier + 1 vmcnt(0) per block,
// 6 independent QK^T MFMA chains, per-WG staggered block order.

typedef short bf16x8 __attribute__((ext_vector_type(8)));
typedef float f32x4  __attribute__((ext_vector_type(4)));

#define MFMA(a, b, c) __builtin_amdgcn_mfma_f32_16x16x32_bf16((a), (b), (c), 0, 0, 0)

typedef __attribute__((address_space(3))) unsigned int lds_u32_t;
typedef __attribute__((address_space(1))) const unsigned int glb_u32_t;

__device__ __forceinline__ unsigned short f32_bf16(float f) {
  unsigned u = __float_as_uint(f);
  u += 0x7FFFu + ((u >> 16) & 1u);   // RNE
  return (unsigned short)(u >> 16);
}
__device__ __forceinline__ float bf16_f32(unsigned short h) {
  return __uint_as_float(((unsigned)h) << 16);
}

// ---------------------------------------------------------------------------
// Prep: split x,m,qp,kp into bf16 hi/lo; output_proj -> bf16; vp -> vp^T bf16.
__global__ void k_prep(const float* __restrict__ x, const float* __restrict__ m,
                       const float* __restrict__ op, const float* __restrict__ qp,
                       const float* __restrict__ kp, const float* __restrict__ vp,
                       unsigned short* __restrict__ xh, unsigned short* __restrict__ xl,
                       unsigned short* __restrict__ mh, unsigned short* __restrict__ ml,
                       unsigned short* __restrict__ opb,
                       unsigned short* __restrict__ qph, unsigned short* __restrict__ qpl,
                       unsigned short* __restrict__ kph, unsigned short* __restrict__ kpl,
                       unsigned short* __restrict__ vpt) {
  const int tid = blockIdx.x * blockDim.x + threadIdx.x;
  const int stride = gridDim.x * blockDim.x;
  for (int i = tid; i < 2097152; i += stride) {
    float v = x[i];
    unsigned short h = f32_bf16(v);
    xh[i] = h; xl[i] = f32_bf16(v - bf16_f32(h));
    float w = m[i];
    unsigned short h2 = f32_bf16(w);
    mh[i] = h2; ml[i] = f32_bf16(w - bf16_f32(h2));
  }
  for (int i = tid; i < 524288; i += stride) {
    opb[i] = f32_bf16(op[i]);
    float q = qp[i];
    unsigned short h = f32_bf16(q);
    qph[i] = h; qpl[i] = f32_bf16(q - bf16_f32(h));
  }
  for (int i = tid; i < 65536; i += stride) {
    float k = kp[i];
    unsigned short h = f32_bf16(k);
    kph[i] = h; kpl[i] = f32_bf16(k - bf16_f32(h));
    const int vc = i >> 8, d = i & 255;
    vpt[i] = f32_bf16(vp[d * 256 + vc]);   // vpt[vc][d]
  }
}

// ---------------------------------------------------------------------------
// W[h][j][i] = sum_k Qp[h,i,k]*Kp[j,k]  (3-pass split MFMA, stored hi/lo).
__global__ __launch_bounds__(256) void k_w(
    const unsigned short* __restrict__ qph, const unsigned short* __restrict__ qpl,
    const unsigned short* __restrict__ kph, const unsigned short* __restrict__ kpl,
    unsigned short* __restrict__ wh, unsigned short* __restrict__ wl) {
  const int jt = blockIdx.x & 7;      // 64 WGs = 8h x 8jt
  const int h  = blockIdx.x >> 3;
  const int wave = threadIdx.x >> 6;
  const int lane = threadIdx.x & 63;
  const int lr = lane & 15, lg = lane >> 4;

  f32x4 acc[2][4];
  const f32x4 z = {0.f, 0.f, 0.f, 0.f};
#pragma unroll
  for (int mi = 0; mi < 2; ++mi)
#pragma unroll
    for (int nt = 0; nt < 4; ++nt) acc[mi][nt] = z;

  for (int ks = 0; ks < 8; ++ks) {
    bf16x8 ah[2], al[2], bh[4], bl[4];
#pragma unroll
    for (int mi = 0; mi < 2; ++mi) {
      const size_t aoff = ((size_t)(jt * 32 + mi * 16 + lr)) * 256 + ks * 32 + lg * 8;
      ah[mi] = *(const bf16x8*)(kph + aoff);
      al[mi] = *(const bf16x8*)(kpl + aoff);
    }
#pragma unroll
    for (int nt = 0; nt < 4; ++nt) {
      const size_t boff = ((size_t)(h * 256 + wave * 64 + nt * 16 + lr)) * 256 + ks * 32 + lg * 8;
      bh[nt] = *(const bf16x8*)(qph + boff);
      bl[nt] = *(const bf16x8*)(qpl + boff);
    }
#pragma unroll
    for (int nt = 0; nt < 4; ++nt)
#pragma unroll
      for (int mi = 0; mi < 2; ++mi) {
        acc[mi][nt] = MFMA(ah[mi], bh[nt], acc[mi][nt]);
        acc[mi][nt] = MFMA(ah[mi], bl[nt], acc[mi][nt]);
        acc[mi][nt] = MFMA(al[mi], bh[nt], acc[mi][nt]);
      }
  }
#pragma unroll
  for (int mi = 0; mi < 2; ++mi)
#pragma unroll
    for (int nt = 0; nt < 4; ++nt)
#pragma unroll
      for (int r = 0; r < 4; ++r) {
        const int j = jt * 32 + mi * 16 + lg * 4 + r;
        const int i = wave * 64 + nt * 16 + lr;
        const float v = acc[mi][nt][r];
        const size_t idx = ((size_t)(h * 256 + j)) * 256 + i;
        const unsigned short hi = f32_bf16(v);
        wh[idx] = hi;
        wl[idx] = f32_bf16(v - bf16_f32(hi));
      }
}

// ---------------------------------------------------------------------------
// vt[b][vc][s] = sum_d m[b,s,d]*vp[d,vc]  (1-pass bf16 MFMA)
__global__ __launch_bounds__(256) void k_v(
    const unsigned short* __restrict__ vpt, const unsigned short* __restrict__ mh,
    unsigned short* __restrict__ vt) {
  const int sc  = blockIdx.x & 3;     // 256 WGs = 8b x 8vct x 4sc
  const int vct = (blockIdx.x >> 2) & 7;
  const int b   = blockIdx.x >> 5;
  const int wave = threadIdx.x >> 6;
  const int lane = threadIdx.x & 63;
  const int lr = lane & 15, lg = lane >> 4;

  f32x4 acc[2][4];
  const f32x4 z = {0.f, 0.f, 0.f, 0.f};
#pragma unroll
  for (int mi = 0; mi < 2; ++mi)
#pragma unroll
    for (int nt = 0; nt < 4; ++nt) acc[mi][nt] = z;

  for (int ks = 0; ks < 8; ++ks) {
    bf16x8 av[2], bv[4];
#pragma unroll
    for (int mi = 0; mi < 2; ++mi)
      av[mi] = *(const bf16x8*)(vpt + ((size_t)(vct * 32 + mi * 16 + lr)) * 256 + ks * 32 + lg * 8);
#pragma unroll
    for (int nt = 0; nt < 4; ++nt)
      bv[nt] = *(const bf16x8*)(mh + ((size_t)(b * 1024 + sc * 256 + wave * 64 + nt * 16 + lr)) * 256 + ks * 32 + lg * 8);
#pragma unroll
    for (int nt = 0; nt < 4; ++nt)
#pragma unroll
      for (int mi = 0; mi < 2; ++mi)
        acc[mi][nt] = MFMA(av[mi], bv[nt], acc[mi][nt]);
  }
#pragma unroll
  for (int mi = 0; mi < 2; ++mi)
#pragma unroll
    for (int nt = 0; nt < 4; ++nt)
#pragma unroll
      for (int r = 0; r < 4; ++r) {
        const int vc = vct * 32 + mi * 16 + lg * 4 + r;
        const int s  = sc * 256 + wave * 64 + nt * 16 + lr;
        vt[((size_t)(b * 256 + vc)) * 1024 + s] = f32_bf16(acc[mi][nt][r]);
      }
}

// ---------------------------------------------------------------------------
// t[b][h][n][d'] = x[b,n,:] @ W[h]  (3-pass split MFMA, batched loads)
__global__ __launch_bounds__(256) void k_t(
    const unsigned short* __restrict__ xh, const unsigned short* __restrict__ xl,
    const unsigned short* __restrict__ wh, const unsigned short* __restrict__ wl,
    unsigned short* __restrict__ th, unsigned short* __restrict__ tl) {
  const int wg = blockIdx.x;        // 2048 = b*h*(1024/32)
  const int mt = wg & 31;
  const int h  = (wg >> 5) & 7;
  const int b  = wg >> 8;
  const int wave = threadIdx.x >> 6;
  const int lane = threadIdx.x & 63;
  const int lr = lane & 15, lg = lane >> 4;

  f32x4 acc[2][4];
  const f32x4 z = {0.f, 0.f, 0.f, 0.f};
#pragma unroll
  for (int mi = 0; mi < 2; ++mi)
#pragma unroll
    for (int nt = 0; nt < 4; ++nt) acc[mi][nt] = z;

  for (int ks = 0; ks < 8; ++ks) {
    bf16x8 ahv[2], alv[2], bh4[4], bl4[4];
#pragma unroll
    for (int mi = 0; mi < 2; ++mi) {
      const size_t aoff = ((size_t)(b * 1024 + mt * 32 + mi * 16 + lr)) * 256 + ks * 32 + lg * 8;
      ahv[mi] = *(const bf16x8*)(xh + aoff);
      alv[mi] = *(const bf16x8*)(xl + aoff);
    }
#pragma unroll
    for (int nt = 0; nt < 4; ++nt) {
      const int dc = wave * 64 + nt * 16 + lr;
      const size_t boff = ((size_t)(h * 256 + dc)) * 256 + ks * 32 + lg * 8;
      bh4[nt] = *(const bf16x8*)(wh + boff);
      bl4[nt] = *(const bf16x8*)(wl + boff);
    }
#pragma unroll
    for (int nt = 0; nt < 4; ++nt)
#pragma unroll
      for (int mi = 0; mi < 2; ++mi) {
        acc[mi][nt] = MFMA(ahv[mi], bh4[nt], acc[mi][nt]);
        acc[mi][nt] = MFMA(ahv[mi], bl4[nt], acc[mi][nt]);
        acc[mi][nt] = MFMA(alv[mi], bh4[nt], acc[mi][nt]);
      }
  }
#pragma unroll
  for (int mi = 0; mi < 2; ++mi)
#pragma unroll
    for (int nt = 0; nt < 4; ++nt)
#pragma unroll
      for (int r = 0; r < 4; ++r) {
        const int row = mt * 32 + mi * 16 + lg * 4 + r;
        const int dc  = wave * 64 + nt * 16 + lr;
        const float v = acc[mi][nt][r];
        const size_t idx = ((size_t)((b * 8 + h) * 1024 + row)) * 256 + dc;
        const unsigned short hi = f32_bf16(v);
        th[idx] = hi;
        tl[idx] = f32_bf16(v - bf16_f32(hi));
      }
}

// ---------------------------------------------------------------------------
// Flash attention per (b, h, 128-q-row tile). 8 waves x 16 q-rows.
// K (hi/lo) double-buffered + V triple-buffered in LDS (112 KB).
// One barrier + one (stall-free) vmcnt(0) per 32-s block.
__global__ __launch_bounds__(512, 2) void k_attn(
    const unsigned short* __restrict__ th, const unsigned short* __restrict__ tl,
    const unsigned short* __restrict__ mh, const unsigned short* __restrict__ ml,
    const unsigned short* __restrict__ vt, unsigned short* __restrict__ ob) {
  __shared__ __align__(16) unsigned short KH[2][8192];   // 32 s x 256 d (swizzled)
  __shared__ __align__(16) unsigned short KL[2][8192];
  __shared__ __align__(16) unsigned short VB[3][8192];   // 256 vc x 32 s (swizzled)

  const int wg0 = blockIdx.x;
  const int wg = (wg0 & 7) * 64 + (wg0 >> 3);   // XCD swizzle: b = XCD id
  const int qt = wg & 7;
  const int h  = (wg >> 3) & 7;
  const int b  = wg >> 6;
  const int wv = threadIdx.x >> 6;
  const int lane = threadIdx.x & 63;
  const int lr = lane & 15, lg = lane >> 4;
  const int start = ((qt << 2) + h) & 31;       // stagger block order per WG

  // Hoist t (B-operand for swapped QK^T): q = lr.
  const size_t trow = ((size_t)((b * 8 + h) * 1024 + qt * 128 + wv * 16 + lr)) * 256;
  bf16x8 Th[8], Tl[8];
#pragma unroll
  for (int d = 0; d < 8; ++d) {
    Th[d] = *(const bf16x8*)(th + trow + d * 32 + lg * 8);
    Tl[d] = *(const bf16x8*)(tl + trow + d * 32 + lg * 8);
  }

  const size_t mbase = (size_t)b * 1024 * 256;
  const size_t vbase = (size_t)b * 256 * 1024;

  // Stage K-block (32s x 256d, hi+lo). Linear LDS dest; source pre-swizzled
  // so LDS 16B-unit u holds global unit u ^ (s&7).
  auto stageK = [&](int lblk, int bi) {
    const int pb = (lblk + start) & 31;
#pragma unroll
    for (int i = 0; i < 2; ++i) {
      const int U = wv * 128 + i * 64 + lane;
      const int s_loc = U >> 5, u_phys = U & 31;
      const int u_log = u_phys ^ (s_loc & 7);
      const size_t soff = mbase + ((size_t)(pb * 32 + s_loc)) * 256 + u_log * 8;
      const int dstb = (wv * 128 + i * 64) * 8;
      __builtin_amdgcn_global_load_lds((glb_u32_t*)(mh + soff), (lds_u32_t*)&KH[bi][dstb], 16, 0, 0);
      __builtin_amdgcn_global_load_lds((glb_u32_t*)(ml + soff), (lds_u32_t*)&KL[bi][dstb], 16, 0, 0);
    }
  };
  // Stage V-block (256vc x 32s from vt). LDS unit u (of 4 per vc-row) holds
  // global unit u ^ (vc&3).
  auto stageV = [&](int lblk, int vi) {
    const int pb = (lblk + start) & 31;
#pragma unroll
    for (int i = 0; i < 2; ++i) {
      const int U = wv * 128 + i * 64 + lane;
      const int vc = U >> 2, u = U & 3;
      const int u_log = u ^ (vc & 3);
      const size_t soff = vbase + (size_t)vc * 1024 + pb * 32 + u_log * 8;
      const int dstb = (wv * 128 + i * 64) * 8;
      __builtin_amdgcn_global_load_lds((glb_u32_t*)(vt + soff), (lds_u32_t*)&VB[vi][dstb], 16, 0, 0);
    }
  };

  f32x4 Oacc[16];
  const f32x4 z = {0.f, 0.f, 0.f, 0.f};
#pragma unroll
  for (int i = 0; i < 16; ++i) Oacc[i] = z;
  float mrun = -1e30f, lrun = 0.0f;
  const float C16 = 0.0901679993f;   // 1/(16*ln2)

  // ---- prologue: stage blocks 0 and 1
  stageK(0, 0); stageV(0, 0);
  stageK(1, 1); stageV(1, 1);
  asm volatile("s_waitcnt vmcnt(0)" ::: "memory");
  __builtin_amdgcn_s_barrier();

  int pvb = 0;   // V buffer for current block (blk % 3)
#pragma unroll 1
  for (int blk = 0; blk < 32; ++blk) {
    const int p = blk & 1;

    // ---- QK^T(blk): 6 independent 8-deep MFMA chains
    f32x4 Sa0 = z, Sb0 = z, Sc0 = z, Sa1 = z, Sb1 = z, Sc1 = z;
#pragma unroll
    for (int d = 0; d < 8; ++d) {
      const int u0 = ((d * 4 + lg) ^ (lr & 7)) * 8;
      const bf16x8 a0h = *(const bf16x8*)&KH[p][lr * 256 + u0];
      const bf16x8 a1h = *(const bf16x8*)&KH[p][(16 + lr) * 256 + u0];
      const bf16x8 a0l = *(const bf16x8*)&KL[p][lr * 256 + u0];
      const bf16x8 a1l = *(const bf16x8*)&KL[p][(16 + lr) * 256 + u0];
      Sa0 = MFMA(a0h, Th[d], Sa0);  Sa1 = MFMA(a1h, Th[d], Sa1);
      Sb0 = MFMA(a0h, Tl[d], Sb0);  Sb1 = MFMA(a1h, Tl[d], Sb1);
      Sc0 = MFMA(a0l, Th[d], Sc0);  Sc1 = MFMA(a1l, Th[d], Sc1);
    }
    const f32x4 S0 = (Sa0 + Sb0) + Sc0;
    const f32x4 S1 = (Sa1 + Sb1) + Sc1;

    // ---- online softmax (q = lr domain)
    float bm = fmaxf(fmaxf(fmaxf(S0[0], S0[1]), fmaxf(S0[2], S0[3])),
                     fmaxf(fmaxf(S1[0], S1[1]), fmaxf(S1[2], S1[3])));
    bm = fmaxf(bm, __shfl_xor(bm, 16));
    bm = fmaxf(bm, __shfl_xor(bm, 32));
    if (!__all(bm - mrun <= 128.0f)) {          // defer-max: THR = 8 nats
      const float mnew = fmaxf(mrun, bm);
      const float sc = exp2f((mrun - mnew) * C16);
      const float s0 = __shfl(sc, lg * 4 + 0);
      const float s1 = __shfl(sc, lg * 4 + 1);
      const float s2 = __shfl(sc, lg * 4 + 2);
      const float s3 = __shfl(sc, lg * 4 + 3);
#pragma unroll
      for (int nt = 0; nt < 16; ++nt) {
        Oacc[nt][0] *= s0; Oacc[nt][1] *= s1; Oacc[nt][2] *= s2; Oacc[nt][3] *= s3;
      }
      lrun *= sc;
      mrun = mnew;
    }
    float p0[4], p1[4];
#pragma unroll
    for (int r = 0; r < 4; ++r) {
      p0[r] = exp2f((S0[r] - mrun) * C16);
      p1[r] = exp2f((S1[r] - mrun) * C16);
    }
    float rs = ((p0[0] + p0[1]) + (p0[2] + p0[3])) +
               ((p1[0] + p1[1]) + (p1[2] + p1[3]));
    rs += __shfl_xor(rs, 16);
    rs += __shfl_xor(rs, 32);
    lrun += rs;

    // ---- pack P to bf16 and redistribute to PV A-fragment layout
    int D00, D01, D10, D11;
    asm("v_cvt_pk_bf16_f32 %0, %1, %2" : "=v"(D00) : "v"(p0[0]), "v"(p0[1]));
    asm("v_cvt_pk_bf16_f32 %0, %1, %2" : "=v"(D01) : "v"(p0[2]), "v"(p0[3]));
    asm("v_cvt_pk_bf16_f32 %0, %1, %2" : "=v"(D10) : "v"(p1[0]), "v"(p1[1]));
    asm("v_cvt_pk_bf16_f32 %0, %1, %2" : "=v"(D11) : "v"(p1[2]), "v"(p1[3]));
    const bool hi2 = (lg & 2) != 0;
    const bool b1  = (lg & 1) != 0;
    const int own0 = hi2 ? D10 : D00;
    const int own1 = hi2 ? D11 : D01;
    const int ant0 = hi2 ? D00 : D10;
    const int ant1 = hi2 ? D01 : D11;
    const int X0 = __shfl_xor(own0, 16);
    const int X1 = __shfl_xor(own1, 16);
    const int W0 = __shfl_xor(ant0, 32);
    const int W1 = __shfl_xor(ant1, 32);
    const int Y0 = __shfl_xor(W0, 16);
    const int Y1 = __shfl_xor(W1, 16);
    const int F0 = hi2 ? (b1 ? X0 : W0) : (b1 ? Y0 : own0);
    const int F1 = hi2 ? (b1 ? X1 : W1) : (b1 ? Y1 : own1);
    const int G0 = hi2 ? (b1 ? own0 : Y0) : (b1 ? W0 : X0);
    const int G1 = hi2 ? (b1 ? own1 : Y1) : (b1 ? W1 : X1);
    union { int u[4]; bf16x8 v; } pa;
    pa.u[0] = F0; pa.u[1] = F1; pa.u[2] = G0; pa.u[3] = G1;

    // ---- sync: everything staged last iteration has landed; all waves done
    // reading K[p] (QK^T above precedes the barrier in program order).
    asm volatile("s_waitcnt vmcnt(0)" ::: "memory");
    __builtin_amdgcn_s_barrier();

    // ---- PV(blk): B-frags from LDS V buffer
#pragma unroll
    for (int nt = 0; nt < 16; ++nt) {
      const bf16x8 bv = *(const bf16x8*)&VB[pvb][(nt * 16 + lr) * 32 + (lg ^ (lr & 3)) * 8];
      Oacc[nt] = MFMA(pa.v, bv, Oacc[nt]);
    }

    // ---- stage blk+2 (K into just-consumed K buffer; V into buffer (blk+2)%3,
    // whose last readers finished before this iteration's barrier)
    if (blk < 30) {
      stageK(blk + 2, p);
      const int sv = (pvb >= 1) ? pvb - 1 : 2;   // (blk+2)%3
      stageV(blk + 2, sv);
    }
    pvb = (pvb == 2) ? 0 : pvb + 1;
  }

  // ---- epilogue
  const float inv = 1.0f / lrun;
  const float i0 = __shfl(inv, lg * 4 + 0);
  const float i1 = __shfl(inv, lg * 4 + 1);
  const float i2 = __shfl(inv, lg * 4 + 2);
  const float i3 = __shfl(inv, lg * 4 + 3);
  const int qg = qt * 128 + wv * 16 + lg * 4;
  const size_t obase = ((size_t)(b * 1024 + qg) * 8 + h) * 256 + lr;
#pragma unroll
  for (int nt = 0; nt < 16; ++nt) {
    ob[obase + 0 * 2048 + nt * 16] = f32_bf16(Oacc[nt][0] * i0);
    ob[obase + 1 * 2048 + nt * 16] = f32_bf16(Oacc[nt][1] * i1);
    ob[obase + 2 * 2048 + nt * 16] = f32_bf16(Oacc[nt][2] * i2);
    ob[obase + 3 * 2048 + nt * 16] = f32_bf16(Oacc[nt][3] * i3);
  }
}

// ---------------------------------------------------------------------------
// out[bn][d] = o[bn][hv] @ OpB[d][hv]^T  (M=8192, K=2048, N=256)
__global__ __launch_bounds__(256) void k_out(
    const unsigned short* __restrict__ ob, const unsigned short* __restrict__ opb,
    float* __restrict__ out) {
  const int wg = blockIdx.x;        // 256 = 8192/32
  const int wave = threadIdx.x >> 6;
  const int lane = threadIdx.x & 63;
  const int lr = lane & 15, lg = lane >> 4;

  f32x4 acc[2][4];
  const f32x4 z = {0.f, 0.f, 0.f, 0.f};
#pragma unroll
  for (int mi = 0; mi < 2; ++mi)
#pragma unroll
    for (int nt = 0; nt < 4; ++nt) acc[mi][nt] = z;

  for (int ks = 0; ks < 64; ++ks) {
    bf16x8 av[2], bv[4];
#pragma unroll
    for (int mi = 0; mi < 2; ++mi) {
      const size_t aoff = ((size_t)(wg * 32 + mi * 16 + lr)) * 2048 + ks * 32 + lg * 8;
      av[mi] = *(const bf16x8*)(ob + aoff);
    }
#pragma unroll
    for (int nt = 0; nt < 4; ++nt) {
      const int dc = wave * 64 + nt * 16 + lr;
      bv[nt] = *(const bf16x8*)(opb + ((size_t)dc) * 2048 + ks * 32 + lg * 8);
    }
#pragma unroll
    for (int nt = 0; nt < 4; ++nt)
#pragma unroll
      for (int mi = 0; mi < 2; ++mi)
        acc[mi][nt] = MFMA(av[mi], bv[nt], acc[mi][nt]);
  }
#pragma unroll
  for (int mi = 0; mi < 2; ++mi)
#pragma unroll
    for (int nt = 0; nt < 4; ++nt)
#pragma unroll
      for (int r = 0; r < 4; ++r) {
        const int row = wg * 32 + mi * 16 + lg * 4 + r;
        const int dc  = wave * 64 + nt * 16 + lr;
        out[(size_t)row * 256 + dc] = acc[mi][nt][r];
      }
}

// ---------------------------------------------------------------------------
extern "C" void kernel_launch(void* const* d_in, const int* in_sizes, int n_in,
                              void* d_out, int out_size, void* d_ws, size_t ws_size,
                              hipStream_t stream) {
  const float* x  = (const float*)d_in[0];
  const float* m  = (const float*)d_in[1];
  const float* qp = (const float*)d_in[2];
  const float* kp = (const float*)d_in[3];
  const float* vp = (const float*)d_in[4];
  const float* op = (const float*)d_in[5];
  float* out = (float*)d_out;

  unsigned short* xh  = (unsigned short*)d_ws;            // [8][1024][256]
  unsigned short* xl  = xh  + 2097152;
  unsigned short* mh  = xl  + 2097152;                    // [8][1024][256]
  unsigned short* ml  = mh  + 2097152;
  unsigned short* wh  = ml  + 2097152;                    // [8][256][256] (j major)
  unsigned short* wl  = wh  + 524288;
  unsigned short* opb = wl  + 524288;                     // [256][2048]
  unsigned short* vt  = opb + 524288;                     // [8][256][1024]
  unsigned short* th  = vt  + 2097152;                    // [8][8][1024][256]
  unsigned short* tl  = th  + 16777216;
  unsigned short* ob  = tl  + 16777216;                   // [8][1024][8][256]
  unsigned short* qph = ob  + 16777216;                   // [8][256][256]
  unsigned short* qpl = qph + 524288;
  unsigned short* kph = qpl + 524288;                     // [256][256]
  unsigned short* kpl = kph + 65536;
  unsigned short* vpt = kpl + 65536;                      // [256][256]

  k_prep<<<2048, 256, 0, stream>>>(x, m, op, qp, kp, vp, xh, xl, mh, ml, opb,
                                   qph, qpl, kph, kpl, vpt);
  k_w   <<<64,   256, 0, stream>>>(qph, qpl, kph, kpl, wh, wl);
  k_v   <<<256,  256, 0, stream>>>(vpt, mh, vt);
  k_t   <<<2048, 256, 0, stream>>>(xh, xl, wh, wl, th, tl);
  k_attn<<<512,  512, 0, stream>>>(th, tl, mh, ml, vt, ob);
  k_out <<<256,  256, 0, stream>>>(ob, opb, out);
}